// Round 10
// baseline (196.839 us; speedup 1.0000x reference)
//
#include <hip/hip_runtime.h>
#include <math.h>

// SSIM loss, fp32 in, B=16 C=3 H=W=512, 11x11 Gaussian (sigma=1.5), zero pad.
// R19: L1-bypass test (sc0) + finalize fusion, on the best structure (R16).
//   Elimination matrix R13-R18: load scheduling (asm ring, R16), LDS
//   round-trip (R17), occupancy (R18: 52% occ, same BW), block queue (R14),
//   fetch pattern (R13/R15) -- ALL falsified as the limiter. Delivered BW
//   pinned at 2.3-2.4 TB/s = 3.9 B/cy/CU = only ~3.5 KB in flight per CU
//   (Little's law @900cy) despite 8+ KB issued per wave. Remaining suspect:
//   per-CU L1/TCP return path (every load allocates an L1 miss entry).
//   Test: sc0 on buffer loads = CDNA L1-bypass read (served from L2).
//   Independent saving: finalize kernel fused away via device-scope
//   atomicAdd(double) + counter-elected last block (16-B hipMemsetAsync on
//   the stream is graph-capture-safe; saves one launch + latency kernel).
// Math identical to R10-R18 (S=x+y, D=x-y planes, f16 pipeline, cv fixup).
// gfx950 v_mfma_f32_16x16x32_f16 layouts (verified R10-R18 pass):
//   A[i][k]: lane = i + 16*(k/8), elem = k%8
//   B[k][j]: lane = j + 16*(k/8), elem = k%8
//   D[r][c]: lane = c + 16*(r/4), reg  = r%4

#define IMG_W 512
#define IMG_H 512
#define PLANES 48
#define TX 64
#define TYS 128
#define RAD 5
#define NT 256
#define GDX (IMG_W / TX)            // 8
#define GDY (IMG_H / TYS)           // 4
#define NBLK (GDX * GDY * PLANES)   // 1536
#define NCH 9                       // hconv 16-row chunks (144 H rows)
#define CSTR 40                     // Ht col stride, f16 (2 slots*16 + 8 pad)
#define PSTR (16 * CSTR)            // Ht plane stride, f16 (640)
#define WSTR (4 * PSTR)             // Ht wave stride, f16 (2560)
#define NUMREC (IMG_W * IMG_H * 4)  // SRD num_records (bytes)
#define CHSTEP (16 * IMG_W * 4)     // voffset step per 16-row chunk (32768)
#define INVW  0.26601181f           // 1 / sum(exp(-(k-5)^2/4.5))
#define GC2   0.32059890f           // (1/4.5) * log2(e)

typedef _Float16 h2 __attribute__((ext_vector_type(2)));
typedef _Float16 h4 __attribute__((ext_vector_type(4)));
typedef _Float16 h8 __attribute__((ext_vector_type(8)));
typedef float f32x4 __attribute__((ext_vector_type(4)));
typedef int i32x4 __attribute__((ext_vector_type(4)));

__device__ __forceinline__ i32x4 make_srd(const float* p) {
    union { i32x4 v; struct { const float* p; unsigned rng; unsigned cfg; } s; } u;
    u.s.p = p; u.s.rng = NUMREC; u.s.cfg = 0x00020000u;
    return u.v;
}

// Counted wait on the asm-issued buffer loads + full scheduling fence so the
// compiler cannot hoist register-only consumers above the wait.
template<int N>
__device__ __forceinline__ void vwait() {
    asm volatile("s_waitcnt vmcnt(%0)" :: "n"(N) : "memory");
    __builtin_amdgcn_sched_barrier(0);
}

__device__ __forceinline__ float exp2_fast(float a) {
#if __has_builtin(__builtin_amdgcn_exp2f)
    return __builtin_amdgcn_exp2f(a);
#else
    return exp2f(a);
#endif
}

// Normalized f32 Gaussian weight w[idx], idx in [0,10], else 0.
__device__ __forceinline__ float wbandf(int idx) {
    const float fd = (float)(idx - 5);
    const float g = exp2_fast(-(fd * fd) * GC2) * INVW;
    return ((unsigned)idx <= 10u) ? g : 0.f;
}

__device__ __forceinline__ h2 pkrtz(float a, float b) {
    auto t = __builtin_amdgcn_cvt_pkrtz(a, b);
    h2 r;
    __builtin_memcpy(&r, &t, sizeof(r));
    return r;
}

__device__ __forceinline__ h4 pack4(f32x4 a) {
    const h2 lo = pkrtz(a[0], a[1]), hi = pkrtz(a[2], a[3]);
    h4 v;
    v[0] = lo.x; v[1] = lo.y; v[2] = hi.x; v[3] = hi.y;
    return v;
}

// One 16-row hconv chunk: regs -> s/d/s2/d2 MFMA -> transposed f16 Ht slot.
__device__ __forceinline__ void hconv_chunk(
    f32x4 xa, f32x4 xb, f32x4 ya, f32x4 yb, h8 whB,
    _Float16* wp)    // = Hw + fc*CSTR + 4*q + slot*16
{
    const f32x4 zz = {0.f, 0.f, 0.f, 0.f};
    const h2 xh0 = pkrtz(xa[0], xa[1]), xh1 = pkrtz(xa[2], xa[3]);
    const h2 xh2 = pkrtz(xb[0], xb[1]), xh3 = pkrtz(xb[2], xb[3]);
    const h2 yh0 = pkrtz(ya[0], ya[1]), yh1 = pkrtz(ya[2], ya[3]);
    const h2 yh2 = pkrtz(yb[0], yb[1]), yh3 = pkrtz(yb[2], yb[3]);
    const h2 s0 = xh0 + yh0, s1 = xh1 + yh1, s2 = xh2 + yh2, s3 = xh3 + yh3;
    const h2 d0 = xh0 - yh0, d1 = xh1 - yh1, d2 = xh2 - yh2, d3 = xh3 - yh3;
    h8 sA, dA;
    sA[0] = s0.x; sA[1] = s0.y; sA[2] = s1.x; sA[3] = s1.y;
    sA[4] = s2.x; sA[5] = s2.y; sA[6] = s3.x; sA[7] = s3.y;
    dA[0] = d0.x; dA[1] = d0.y; dA[2] = d1.x; dA[3] = d1.y;
    dA[4] = d2.x; dA[5] = d2.y; dA[6] = d3.x; dA[7] = d3.y;
    const h8 s2A = sA * sA;                       // v_pk_mul_f16
    const h8 d2A = dA * dA;
    const f32x4 hS  = __builtin_amdgcn_mfma_f32_16x16x32_f16(sA,  whB, zz, 0, 0, 0);
    const f32x4 hD  = __builtin_amdgcn_mfma_f32_16x16x32_f16(dA,  whB, zz, 0, 0, 0);
    const f32x4 hS2 = __builtin_amdgcn_mfma_f32_16x16x32_f16(s2A, whB, zz, 0, 0, 0);
    const f32x4 hD2 = __builtin_amdgcn_mfma_f32_16x16x32_f16(d2A, whB, zz, 0, 0, 0);
    *(h4*)(wp + 0 * PSTR) = pack4(hS);            // ds_write_b64
    *(h4*)(wp + 1 * PSTR) = pack4(hD);
    *(h4*)(wp + 2 * PSTR) = pack4(hS2);
    *(h4*)(wp + 3 * PSTR) = pack4(hD2);
}

// SSIM map for one completed out-chunk (4 rows of one col per lane).
__device__ __forceinline__ float mapsum(f32x4 aS, f32x4 aD, f32x4 aS2, f32x4 aD2,
                                        float cv)
{
    float local = 0.f;
    #pragma unroll
    for (int r = 0; r < 4; ++r) {
        const float mS = aS[r]  * cv, mD = aD[r]  * cv;
        const float eS = aS2[r] * cv, eD = aD2[r] * cv;
        const float ms2 = mS * mS, md2 = mD * mD;
        const float Pm = 0.5f * (ms2 - md2);   // = 2*mu_x*mu_y
        const float Qm = 0.5f * (ms2 + md2);   // = mu_x^2 + mu_y^2
        const float Pe = 0.5f * (eS - eD);     // = 2*E[xy]
        const float Qe = 0.5f * (eS + eD);     // = E[x^2 + y^2]
        const float c1 = 1e-4f, c2 = 9e-4f;
        const float num = (Pm + c1) * (Pe - Pm + c2);
        const float den = (Qm + c1) * (Qe - Qm + c2) + 1e-8f;
        local += num * __builtin_amdgcn_rcpf(den);
    }
    return local;
}

#define MFMA16(A, B, C) __builtin_amdgcn_mfma_f32_16x16x32_f16((A), (B), (C), 0, 0, 0)

// Issue one chunk's 4 loads (order fixed: asm volatile). sc0 = L1 bypass.
#define ISSUE(slot) do {                                                      \
    asm volatile("buffer_load_dwordx4 %0, %1, %2, 0 offen sc0"                \
                 : "=v"(LXA[slot]) : "v"(voff), "s"(srdx));                   \
    asm volatile("buffer_load_dwordx4 %0, %1, %2, 0 offen offset:16 sc0"      \
                 : "=v"(LXB[slot]) : "v"(voff), "s"(srdx));                   \
    asm volatile("buffer_load_dwordx4 %0, %1, %2, 0 offen sc0"                \
                 : "=v"(LYA[slot]) : "v"(voff), "s"(srdy));                   \
    asm volatile("buffer_load_dwordx4 %0, %1, %2, 0 offen offset:16 sc0"      \
                 : "=v"(LYB[slot]) : "v"(voff), "s"(srdy));                   \
    voff += CHSTEP;                                                           \
} while (0)

// vconv for out-chunk m (at iteration c = m+2): LDS-only, no vmem dep.
#define VCONV(C) do {                                                         \
    const _Float16* rp = rbase + ((((C) + qh) & 1) << 4);                     \
    const h8 B0 = *(const h8*)(rp + 0 * PSTR);   /* ds_read_b128 x4 */        \
    const h8 B1 = *(const h8*)(rp + 1 * PSTR);                                \
    const h8 B2 = *(const h8*)(rp + 2 * PSTR);                                \
    const h8 B3 = *(const h8*)(rp + 3 * PSTR);                                \
    const f32x4 aS  = MFMA16(wvA, B0, zz);                                    \
    const f32x4 aD  = MFMA16(wvA, B1, zz);                                    \
    const f32x4 aS2 = MFMA16(wvA, B2, zz);                                    \
    const f32x4 aD2 = MFMA16(wvA, B3, zz);                                    \
    local += mapsum(aS, aD, aS2, aD2, cv);                                    \
} while (0)

__global__ __launch_bounds__(NT, 4) void ssim_tile_kernel(
    const float* __restrict__ x, const float* __restrict__ y,
    double* __restrict__ acc, unsigned* __restrict__ cnt,
    float* __restrict__ out)
{
    __shared__ __align__(16) _Float16 Ht[4 * WSTR];   // 20480 B
    __shared__ float wave_sums[NT / 64];

    const int tid = threadIdx.x;
    const int l = tid & 63, wid = tid >> 6;
    const int q = l >> 4, fc = l & 15;
    const int ql = q & 1, qh = q >> 1;

    const int plane = blockIdx.z;
    const i32x4 srdx = make_srd(x + (size_t)plane * IMG_H * IMG_W);
    const i32x4 srdy = make_srd(y + (size_t)plane * IMG_H * IMG_W);
    const int C0 = blockIdx.x * TX;
    const int R0 = blockIdx.y * TYS;
    const int c0 = 16 * wid;                    // this wave's out-col base
    const int gcol = C0 + c0 - 8 + 8 * q;       // A-frag global col start
    // Row OOB -> voffset outside [0,NUMREC) -> HW returns 0 (zero-pad).
    // Col OOB lanes (gcol=-8 or 512): permanently-OOB voffset.
    int voff = ((unsigned)gcol < (unsigned)IMG_W)
             ? (((R0 - RAD + fc) << 11) + (gcol << 2)) : 0x60000000;

    // ---- Prologue: issue chunks 0,1,2 into ring slots 0,1,2 ----
    f32x4 LXA[3], LXB[3], LYA[3], LYB[3];
    ISSUE(0); ISSUE(1); ISSUE(2);

    // ---- Weight setup (executes under the 12 in-flight loads) ----
    float s2w = 0.f;
    #pragma unroll
    for (int k = 0; k <= 10; ++k) s2w += (float)(_Float16)wbandf(k);
    const float cv = 1.f / (s2w * s2w);

    h8 whB, wvA;                 // hconv B-frag w[t-u-3], vconv A-frag w[t-u]
    #pragma unroll
    for (int e = 0; e < 8; ++e) {
        whB[e] = (_Float16)wbandf(8 * q + e - fc - 3);
        wvA[e] = (_Float16)wbandf(8 * q + e - fc);
    }

    _Float16* const Hw = Ht + wid * WSTR;                    // wave's region
    _Float16* const hwr = Hw + fc * CSTR + 4 * q;            // write base (+slot*16)
    const _Float16* const rbase = Hw + fc * CSTR + 8 * ql;   // read base (+slot*16)

    const f32x4 zz = {0.f, 0.f, 0.f, 0.f};
    float local = 0.f;

    // ---- Main loop: vconv m=c-2 (LDS-only, hides load latency) |
    //      wait chunk c | hconv c | issue c+3 ----
    #pragma unroll
    for (int c = 0; c < NCH; ++c) {
        if (c >= 2) VCONV(c);            // reads LDS chunks c-2 (slot c&1), c-1
        if (c <= 6) vwait<8>();          // retire chunk c (12 outstanding)
        else if (c == 7) vwait<4>();     // chunks 7,8 outstanding
        else vwait<0>();
        // hconv chunk c -> LDS slot c&1 (overwrites chunk c-2 AFTER the
        // VCONV reads above; same-wave DS ops execute in order)
        hconv_chunk(LXA[c % 3], LXB[c % 3], LYA[c % 3], LYB[c % 3],
                    whB, hwr + ((c & 1) << 4));
        if (c + 3 < NCH) ISSUE(c % 3);   // refill freed ring slot w/ chunk c+3
    }

    // ---- Epilogue: out chunk m=7 (reads LDS chunks 7,8) ----
    VCONV(9);

    // ---- Block reduction -> fused global accumulation ----
    #pragma unroll
    for (int off = 32; off > 0; off >>= 1)
        local += __shfl_down(local, off, 64);
    if (l == 0) wave_sums[wid] = local;
    __syncthreads();
    if (tid == 0) {
        const double s = (double)wave_sums[0] + (double)wave_sums[1]
                       + (double)wave_sums[2] + (double)wave_sums[3];
        atomicAdd(acc, s);               // device-scope (L2 coherence point)
        __threadfence();
        const unsigned t = atomicAdd(cnt, 1u);
        if (t == NBLK - 1) {
            // atomic RMW routes to the home slice -> sees all prior adds
            const double tot = atomicAdd(acc, 0.0);
            const double n = (double)PLANES * IMG_H * IMG_W;
            out[0] = (float)(1.0 - tot / n);
        }
    }
}

extern "C" void kernel_launch(void* const* d_in, const int* in_sizes, int n_in,
                              void* d_out, int out_size, void* d_ws, size_t ws_size,
                              hipStream_t stream)
{
    const float* x = (const float*)d_in[0];
    const float* y = (const float*)d_in[1];
    float* out = (float*)d_out;
    double* acc = (double*)d_ws;               // [0]: sum accumulator
    unsigned* cnt = (unsigned*)((char*)d_ws + 8);  // [8]: block counter

    hipMemsetAsync(d_ws, 0, 16, stream);       // capture-safe memset node

    dim3 grid(GDX, GDY, PLANES);
    ssim_tile_kernel<<<grid, NT, 0, stream>>>(x, y, acc, cnt, out);
}

// Round 11
// 185.974 us; speedup vs baseline: 1.0584x; 1.0584x over previous
//
#include <hip/hip_runtime.h>
#include <math.h>

// SSIM loss, fp32 in, B=16 C=3 H=W=512, 11x11 Gaussian (sigma=1.5), zero pad.
// R20: coalesced block-cooperative staging test.
//   R19 (sc0 L1-bypass) collapsed to 0.9 TB/s -> L1 serves most of the 227MB
//   request volume; best structure services requests at 5.4 TB/s while HBM
//   pins at 2.4. Remaining theory: the per-lane-scattered pattern (each load
//   instr = 16 rows x 2 lines = 32 line-spans at 2KB stride) limits the
//   TA/TCP line pipeline; the 6.3 TB/s copy ubench issues contiguous 1KB
//   bursts (4-5 line-spans/instr).
//   Change: global loads become block-cooperative CONTIGUOUS staging of a
//   16-row x 80-col chunk (thread->(row,col4) map; 320B contiguous runs),
//   s/d f16 into LDS; waves build A-frags from LDS (ds_read_b128). Also
//   removes the 2x column over-issue (staged once, read by 4 waves):
//   request volume 227 -> 142 MB. Loads for chunk c+1 asm-issued (NO sc0)
//   before the barrier -> fly under VCONV+hconv of chunk c. One barrier per
//   chunk; double-buffered input slots (hazard: write slot (c+1)&1 at iter
//   c+1 top is after all reads of it via BAR(c) -- each wave's hconv(c-1)
//   precedes its BAR(c) arrival).
//   hconv/Ht/vconv pipeline = R16 verbatim (verified R10-R19).
// gfx950 v_mfma_f32_16x16x32_f16 layouts (verified R10-R19 pass):
//   A[i][k]: lane = i + 16*(k/8), elem = k%8
//   B[k][j]: lane = j + 16*(k/8), elem = k%8
//   D[r][c]: lane = c + 16*(r/4), reg  = r%4

#define IMG_W 512
#define IMG_H 512
#define PLANES 48
#define TX 64
#define TYS 128
#define RAD 5
#define NT 256
#define GDX (IMG_W / TX)            // 8
#define GDY (IMG_H / TYS)           // 4
#define NBLK (GDX * GDY * PLANES)   // 1536
#define NCH 9                       // hconv 16-row chunks (144 H rows)
#define SC4 20                      // staged float4 per row (80 cols)
#define SSTR 88                     // staged f16 row stride (176 B)
#define CSTR 40                     // Ht col stride, f16 (2 slots*16 + 8 pad)
#define PSTR (16 * CSTR)            // Ht plane stride, f16 (640)
#define WSTR (4 * PSTR)             // Ht wave stride, f16 (2560)
#define NUMREC (IMG_W * IMG_H * 4)  // SRD num_records (bytes)
#define CHSTEP (16 * IMG_W * 4)     // voffset step per 16-row chunk (32768)
#define INVW  0.26601181f           // 1 / sum(exp(-(k-5)^2/4.5))
#define GC2   0.32059890f           // (1/4.5) * log2(e)

typedef _Float16 h2 __attribute__((ext_vector_type(2)));
typedef _Float16 h4 __attribute__((ext_vector_type(4)));
typedef _Float16 h8 __attribute__((ext_vector_type(8)));
typedef float f32x4 __attribute__((ext_vector_type(4)));
typedef int i32x4 __attribute__((ext_vector_type(4)));

__device__ __forceinline__ i32x4 make_srd(const float* p) {
    union { i32x4 v; struct { const float* p; unsigned rng; unsigned cfg; } s; } u;
    u.s.p = p; u.s.rng = NUMREC; u.s.cfg = 0x00020000u;
    return u.v;
}

// Counted wait on asm-issued buffer loads + scheduling fence (rule #18).
template<int N>
__device__ __forceinline__ void vwait() {
    asm volatile("s_waitcnt vmcnt(%0)" :: "n"(N) : "memory");
    __builtin_amdgcn_sched_barrier(0);
}

__device__ __forceinline__ float exp2_fast(float a) {
#if __has_builtin(__builtin_amdgcn_exp2f)
    return __builtin_amdgcn_exp2f(a);
#else
    return exp2f(a);
#endif
}

// Normalized f32 Gaussian weight w[idx], idx in [0,10], else 0.
__device__ __forceinline__ float wbandf(int idx) {
    const float fd = (float)(idx - 5);
    const float g = exp2_fast(-(fd * fd) * GC2) * INVW;
    return ((unsigned)idx <= 10u) ? g : 0.f;
}

__device__ __forceinline__ h2 pkrtz(float a, float b) {
    auto t = __builtin_amdgcn_cvt_pkrtz(a, b);
    h2 r;
    __builtin_memcpy(&r, &t, sizeof(r));
    return r;
}

__device__ __forceinline__ h4 pack4(f32x4 a) {
    const h2 lo = pkrtz(a[0], a[1]), hi = pkrtz(a[2], a[3]);
    h4 v;
    v[0] = lo.x; v[1] = lo.y; v[2] = hi.x; v[3] = hi.y;
    return v;
}

// SSIM map for one completed out-chunk (4 rows of one col per lane).
__device__ __forceinline__ float mapsum(f32x4 aS, f32x4 aD, f32x4 aS2, f32x4 aD2,
                                        float cv)
{
    float local = 0.f;
    #pragma unroll
    for (int r = 0; r < 4; ++r) {
        const float mS = aS[r]  * cv, mD = aD[r]  * cv;
        const float eS = aS2[r] * cv, eD = aD2[r] * cv;
        const float ms2 = mS * mS, md2 = mD * mD;
        const float Pm = 0.5f * (ms2 - md2);   // = 2*mu_x*mu_y
        const float Qm = 0.5f * (ms2 + md2);   // = mu_x^2 + mu_y^2
        const float Pe = 0.5f * (eS - eD);     // = 2*E[xy]
        const float Qe = 0.5f * (eS + eD);     // = E[x^2 + y^2]
        const float c1 = 1e-4f, c2 = 9e-4f;
        const float num = (Pm + c1) * (Pe - Pm + c2);
        const float den = (Qm + c1) * (Qe - Qm + c2) + 1e-8f;
        local += num * __builtin_amdgcn_rcpf(den);
    }
    return local;
}

#define MFMA16(A, B, C) __builtin_amdgcn_mfma_f32_16x16x32_f16((A), (B), (C), 0, 0, 0)

// Issue this thread's staging loads for the next chunk (order fixed).
#define ISSUE() do {                                                          \
    asm volatile("buffer_load_dwordx4 %0, %1, %2, 0 offen"                    \
                 : "=v"(X0) : "v"(voff0), "s"(srdx));                         \
    asm volatile("buffer_load_dwordx4 %0, %1, %2, 0 offen"                    \
                 : "=v"(Y0) : "v"(voff0), "s"(srdy));                         \
    if (has1) {                                                               \
        asm volatile("buffer_load_dwordx4 %0, %1, %2, 0 offen"                \
                     : "=v"(X1) : "v"(voff1), "s"(srdx));                     \
        asm volatile("buffer_load_dwordx4 %0, %1, %2, 0 offen"                \
                     : "=v"(Y1) : "v"(voff1), "s"(srdy));                     \
    }                                                                         \
    voff0 += CHSTEP; voff1 += CHSTEP;                                         \
} while (0)

// Convert one staged position (X,Y f32x4) to s,d f16x4 and write LDS.
#define STAGE_WRITE(X, Y, ROW, C4, SLOT) do {                                 \
    const h2 xl = pkrtz((X)[0], (X)[1]), xh = pkrtz((X)[2], (X)[3]);          \
    const h2 yl = pkrtz((Y)[0], (Y)[1]), yh = pkrtz((Y)[2], (Y)[3]);          \
    const h2 sl = xl + yl, sh = xh + yh;                                      \
    const h2 dl = xl - yl, dh = xh - yh;                                      \
    h4 sv, dv;                                                                \
    sv[0] = sl.x; sv[1] = sl.y; sv[2] = sh.x; sv[3] = sh.y;                   \
    dv[0] = dl.x; dv[1] = dl.y; dv[2] = dh.x; dv[3] = dh.y;                   \
    *(h4*)&sdIn[SLOT][0][ROW][4 * (C4)] = sv;                                 \
    *(h4*)&sdIn[SLOT][1][ROW][4 * (C4)] = dv;                                 \
} while (0)

// vconv for out-chunk m (at iteration c = m+2): LDS-only (R16 verbatim).
#define VCONV(C) do {                                                         \
    const _Float16* rp = rbase + ((((C) + qh) & 1) << 4);                     \
    const h8 B0 = *(const h8*)(rp + 0 * PSTR);   /* ds_read_b128 x4 */        \
    const h8 B1 = *(const h8*)(rp + 1 * PSTR);                                \
    const h8 B2 = *(const h8*)(rp + 2 * PSTR);                                \
    const h8 B3 = *(const h8*)(rp + 3 * PSTR);                                \
    const f32x4 aS  = MFMA16(wvA, B0, zz);                                    \
    const f32x4 aD  = MFMA16(wvA, B1, zz);                                    \
    const f32x4 aS2 = MFMA16(wvA, B2, zz);                                    \
    const f32x4 aD2 = MFMA16(wvA, B3, zz);                                    \
    local += mapsum(aS, aD, aS2, aD2, cv);                                    \
} while (0)

__global__ __launch_bounds__(NT, 4) void ssim_tile_kernel(
    const float* __restrict__ x, const float* __restrict__ y,
    float* __restrict__ partials)
{
    __shared__ _Float16 sdIn[2][2][16][SSTR];         // 11264 B (slot,plane)
    __shared__ __align__(16) _Float16 Ht[4 * WSTR];   // 20480 B
    __shared__ float wave_sums[NT / 64];

    const int tid = threadIdx.x;
    const int l = tid & 63, wid = tid >> 6;
    const int q = l >> 4, fc = l & 15;
    const int ql = q & 1, qh = q >> 1;

    const int plane = blockIdx.z;
    const i32x4 srdx = make_srd(x + (size_t)plane * IMG_H * IMG_W);
    const i32x4 srdy = make_srd(y + (size_t)plane * IMG_H * IMG_W);
    const int C0 = blockIdx.x * TX;
    const int R0 = blockIdx.y * TYS;
    const int c0 = 16 * wid;                    // this wave's out-col base

    // ---- Staging map: position p -> (row, c4); p0 = tid, p1 = 256+tid ----
    const int row0 = tid / SC4, c40 = tid - SC4 * row0;
    const bool has1 = tid < 320 - NT;           // 64 threads take 2nd position
    const int p1 = NT + tid;
    const int row1 = p1 / SC4, c41 = p1 - SC4 * row1;
    const int gcol0 = C0 - 8 + 4 * c40;         // staged col 0 <-> C0-8
    const int gcol1 = C0 - 8 + 4 * c41;
    // Row OOB -> voffset outside [0,NUMREC) -> HW returns 0 (zero-pad).
    // Col OOB positions: permanently-OOB voffset (stays OOB under += CHSTEP).
    int voff0 = ((unsigned)gcol0 < (unsigned)IMG_W)
              ? (((R0 - RAD + row0) << 11) + (gcol0 << 2)) : 0x60000000;
    int voff1 = ((unsigned)gcol1 < (unsigned)IMG_W)
              ? (((R0 - RAD + row1) << 11) + (gcol1 << 2)) : 0x60000000;

    // ---- Prologue: issue chunk 0 staging loads ----
    f32x4 X0, Y0, X1, Y1;
    ISSUE();

    // ---- Weight setup (executes under the in-flight loads) ----
    float s2w = 0.f;
    #pragma unroll
    for (int k = 0; k <= 10; ++k) s2w += (float)(_Float16)wbandf(k);
    const float cv = 1.f / (s2w * s2w);

    h8 whB, wvA;                 // hconv B-frag w[t-u-3], vconv A-frag w[t-u]
    #pragma unroll
    for (int e = 0; e < 8; ++e) {
        whB[e] = (_Float16)wbandf(8 * q + e - fc - 3);
        wvA[e] = (_Float16)wbandf(8 * q + e - fc);
    }

    _Float16* const Hw = Ht + wid * WSTR;                    // wave's region
    _Float16* const hwr = Hw + fc * CSTR + 4 * q;            // write base (+slot*16)
    const _Float16* const rbase = Hw + fc * CSTR + 8 * ql;   // read base (+slot*16)

    const f32x4 zz = {0.f, 0.f, 0.f, 0.f};
    float local = 0.f;

    // ---- Main loop over chunks c = 0..8 ----
    // [wait loads; LDS-write chunk c; issue c+1] BAR [VCONV(c); hconv(c)]
    #pragma unroll
    for (int c = 0; c < NCH; ++c) {
        vwait<0>();
        STAGE_WRITE(X0, Y0, row0, c40, c & 1);
        if (has1) STAGE_WRITE(X1, Y1, row1, c41, c & 1);
        if (c + 1 < NCH) ISSUE();        // chunk c+1 flies under BAR+MFMA work
        __syncthreads();

        if (c >= 2) VCONV(c);            // reads Ht chunks c-2 (slot c&1), c-1

        // hconv chunk c: A-frags from staged LDS -> Ht slot c&1 (overwrites
        // chunk c-2 AFTER the VCONV reads; same-wave DS ops are in order)
        {
            const h8 sA = *(const h8*)&sdIn[c & 1][0][fc][c0 + 8 * q];
            const h8 dA = *(const h8*)&sdIn[c & 1][1][fc][c0 + 8 * q];
            const h8 s2A = sA * sA;                  // v_pk_mul_f16
            const h8 d2A = dA * dA;
            const f32x4 hS  = MFMA16(sA,  whB, zz);
            const f32x4 hD  = MFMA16(dA,  whB, zz);
            const f32x4 hS2 = MFMA16(s2A, whB, zz);
            const f32x4 hD2 = MFMA16(d2A, whB, zz);
            _Float16* wp = hwr + ((c & 1) << 4);
            *(h4*)(wp + 0 * PSTR) = pack4(hS);       // ds_write_b64
            *(h4*)(wp + 1 * PSTR) = pack4(hD);
            *(h4*)(wp + 2 * PSTR) = pack4(hS2);
            *(h4*)(wp + 3 * PSTR) = pack4(hD2);
        }
    }

    // ---- Epilogue: out chunk m=7 (reads Ht chunks 7,8) ----
    VCONV(9);

    // ---- Block reduction -> one partial per block ----
    #pragma unroll
    for (int off = 32; off > 0; off >>= 1)
        local += __shfl_down(local, off, 64);
    if (l == 0) wave_sums[wid] = local;
    __syncthreads();
    if (tid == 0) {
        const float s = wave_sums[0] + wave_sums[1] + wave_sums[2] + wave_sums[3];
        const int bid = blockIdx.x + GDX * (blockIdx.y + GDY * blockIdx.z);
        partials[bid] = s;
    }
}

__global__ __launch_bounds__(256) void ssim_finalize_kernel(
    const float* __restrict__ partials, float* __restrict__ out)
{
    const int tid = threadIdx.x;
    double s = 0.0;
    #pragma unroll 4
    for (int i = tid; i < NBLK; i += 256) s += (double)partials[i];
    #pragma unroll
    for (int off = 32; off > 0; off >>= 1)
        s += __shfl_down(s, off, 64);
    __shared__ double ws_[256 / 64];
    const int lane = tid & 63, wv = tid >> 6;
    if (lane == 0) ws_[wv] = s;
    __syncthreads();
    if (tid == 0) {
        const double t = ws_[0] + ws_[1] + ws_[2] + ws_[3];
        const double n = (double)PLANES * IMG_H * IMG_W;
        out[0] = (float)(1.0 - t / n);
    }
}

extern "C" void kernel_launch(void* const* d_in, const int* in_sizes, int n_in,
                              void* d_out, int out_size, void* d_ws, size_t ws_size,
                              hipStream_t stream)
{
    const float* x = (const float*)d_in[0];
    const float* y = (const float*)d_in[1];
    float* out = (float*)d_out;
    float* partials = (float*)d_ws;   // NBLK floats, fully overwritten each call

    dim3 grid(GDX, GDY, PLANES);
    ssim_tile_kernel<<<grid, NT, 0, stream>>>(x, y, partials);
    ssim_finalize_kernel<<<1, 256, 0, stream>>>(partials, out);
}

// Round 12
// 131.118 us; speedup vs baseline: 1.5012x; 1.4184x over previous
//
#include <hip/hip_runtime.h>
#include <math.h>

// SSIM loss, fp32 in, B=16 C=3 H=W=512, 11x11 Gaussian (sigma=1.5), zero pad.
// R21: R16 (best, 42.3us) + XCD swizzle + TYS=256 + issue-early.
//   R20 post-mortem: coalesced staging died of scratch spills (WRITE_SIZE
//   72MB, occupancy 1%) -- asm lifetimes across barriers. R10+R20 falsify
//   coalesced staging as the lever. R15 proved HBM serves this scattered
//   pattern at 3.3 TB/s when demand exists; the untested delta on the best
//   structure is cross-block L2 locality (T1).
//   1. XCD-aware bijective swizzle (768%8==0): bid -> sid=(bid%8)*96+bid/8;
//      each XCD gets 96 contiguous blocks = 6 whole planes -> halo re-reads
//      become per-XCD L2 hits instead of HBM re-fetches.
//   2. TYS=256 (NCH=17): row halo 1.125x -> 1.0625x, setup amortized 2x.
//   3. Issue-early: ring slot copied to locals, refill issued BEFORE the
//      hconv MFMAs (SSA keeps old values; loads fly under hconv too).
//   hconv/Ht/vconv pipeline, ring depth 3, vwait discipline = R16 verbatim.
// gfx950 v_mfma_f32_16x16x32_f16 layouts (verified R10-R20 pass):
//   A[i][k]: lane = i + 16*(k/8), elem = k%8
//   B[k][j]: lane = j + 16*(k/8), elem = k%8
//   D[r][c]: lane = c + 16*(r/4), reg  = r%4

#define IMG_W 512
#define IMG_H 512
#define PLANES 48
#define TX 64
#define TYS 256
#define RAD 5
#define NT 256
#define GDX (IMG_W / TX)            // 8
#define GDY (IMG_H / TYS)           // 2
#define NBLK (GDX * GDY * PLANES)   // 768
#define NCH 17                      // hconv 16-row chunks (272 H rows)
#define CSTR 40                     // Ht col stride, f16 (2 slots*16 + 8 pad)
#define PSTR (16 * CSTR)            // Ht plane stride, f16 (640)
#define WSTR (4 * PSTR)             // Ht wave stride, f16 (2560)
#define NUMREC (IMG_W * IMG_H * 4)  // SRD num_records (bytes)
#define CHSTEP (16 * IMG_W * 4)     // voffset step per 16-row chunk (32768)
#define INVW  0.26601181f           // 1 / sum(exp(-(k-5)^2/4.5))
#define GC2   0.32059890f           // (1/4.5) * log2(e)

typedef _Float16 h2 __attribute__((ext_vector_type(2)));
typedef _Float16 h4 __attribute__((ext_vector_type(4)));
typedef _Float16 h8 __attribute__((ext_vector_type(8)));
typedef float f32x4 __attribute__((ext_vector_type(4)));
typedef int i32x4 __attribute__((ext_vector_type(4)));

__device__ __forceinline__ i32x4 make_srd(const float* p) {
    union { i32x4 v; struct { const float* p; unsigned rng; unsigned cfg; } s; } u;
    u.s.p = p; u.s.rng = NUMREC; u.s.cfg = 0x00020000u;
    return u.v;
}

// Counted wait on asm-issued buffer loads + scheduling fence (rule #18).
template<int N>
__device__ __forceinline__ void vwait() {
    asm volatile("s_waitcnt vmcnt(%0)" :: "n"(N) : "memory");
    __builtin_amdgcn_sched_barrier(0);
}

__device__ __forceinline__ float exp2_fast(float a) {
#if __has_builtin(__builtin_amdgcn_exp2f)
    return __builtin_amdgcn_exp2f(a);
#else
    return exp2f(a);
#endif
}

// Normalized f32 Gaussian weight w[idx], idx in [0,10], else 0.
__device__ __forceinline__ float wbandf(int idx) {
    const float fd = (float)(idx - 5);
    const float g = exp2_fast(-(fd * fd) * GC2) * INVW;
    return ((unsigned)idx <= 10u) ? g : 0.f;
}

__device__ __forceinline__ h2 pkrtz(float a, float b) {
    auto t = __builtin_amdgcn_cvt_pkrtz(a, b);
    h2 r;
    __builtin_memcpy(&r, &t, sizeof(r));
    return r;
}

__device__ __forceinline__ h4 pack4(f32x4 a) {
    const h2 lo = pkrtz(a[0], a[1]), hi = pkrtz(a[2], a[3]);
    h4 v;
    v[0] = lo.x; v[1] = lo.y; v[2] = hi.x; v[3] = hi.y;
    return v;
}

// One 16-row hconv chunk: regs -> s/d/s2/d2 MFMA -> transposed f16 Ht slot.
__device__ __forceinline__ void hconv_chunk(
    f32x4 xa, f32x4 xb, f32x4 ya, f32x4 yb, h8 whB,
    _Float16* wp)    // = Hw + fc*CSTR + 4*q + slot*16
{
    const f32x4 zz = {0.f, 0.f, 0.f, 0.f};
    const h2 xh0 = pkrtz(xa[0], xa[1]), xh1 = pkrtz(xa[2], xa[3]);
    const h2 xh2 = pkrtz(xb[0], xb[1]), xh3 = pkrtz(xb[2], xb[3]);
    const h2 yh0 = pkrtz(ya[0], ya[1]), yh1 = pkrtz(ya[2], ya[3]);
    const h2 yh2 = pkrtz(yb[0], yb[1]), yh3 = pkrtz(yb[2], yb[3]);
    const h2 s0 = xh0 + yh0, s1 = xh1 + yh1, s2 = xh2 + yh2, s3 = xh3 + yh3;
    const h2 d0 = xh0 - yh0, d1 = xh1 - yh1, d2 = xh2 - yh2, d3 = xh3 - yh3;
    h8 sA, dA;
    sA[0] = s0.x; sA[1] = s0.y; sA[2] = s1.x; sA[3] = s1.y;
    sA[4] = s2.x; sA[5] = s2.y; sA[6] = s3.x; sA[7] = s3.y;
    dA[0] = d0.x; dA[1] = d0.y; dA[2] = d1.x; dA[3] = d1.y;
    dA[4] = d2.x; dA[5] = d2.y; dA[6] = d3.x; dA[7] = d3.y;
    const h8 s2A = sA * sA;                       // v_pk_mul_f16
    const h8 d2A = dA * dA;
    const f32x4 hS  = __builtin_amdgcn_mfma_f32_16x16x32_f16(sA,  whB, zz, 0, 0, 0);
    const f32x4 hD  = __builtin_amdgcn_mfma_f32_16x16x32_f16(dA,  whB, zz, 0, 0, 0);
    const f32x4 hS2 = __builtin_amdgcn_mfma_f32_16x16x32_f16(s2A, whB, zz, 0, 0, 0);
    const f32x4 hD2 = __builtin_amdgcn_mfma_f32_16x16x32_f16(d2A, whB, zz, 0, 0, 0);
    *(h4*)(wp + 0 * PSTR) = pack4(hS);            // ds_write_b64
    *(h4*)(wp + 1 * PSTR) = pack4(hD);
    *(h4*)(wp + 2 * PSTR) = pack4(hS2);
    *(h4*)(wp + 3 * PSTR) = pack4(hD2);
}

// SSIM map for one completed out-chunk (4 rows of one col per lane).
__device__ __forceinline__ float mapsum(f32x4 aS, f32x4 aD, f32x4 aS2, f32x4 aD2,
                                        float cv)
{
    float local = 0.f;
    #pragma unroll
    for (int r = 0; r < 4; ++r) {
        const float mS = aS[r]  * cv, mD = aD[r]  * cv;
        const float eS = aS2[r] * cv, eD = aD2[r] * cv;
        const float ms2 = mS * mS, md2 = mD * mD;
        const float Pm = 0.5f * (ms2 - md2);   // = 2*mu_x*mu_y
        const float Qm = 0.5f * (ms2 + md2);   // = mu_x^2 + mu_y^2
        const float Pe = 0.5f * (eS - eD);     // = 2*E[xy]
        const float Qe = 0.5f * (eS + eD);     // = E[x^2 + y^2]
        const float c1 = 1e-4f, c2 = 9e-4f;
        const float num = (Pm + c1) * (Pe - Pm + c2);
        const float den = (Qm + c1) * (Qe - Qm + c2) + 1e-8f;
        local += num * __builtin_amdgcn_rcpf(den);
    }
    return local;
}

#define MFMA16(A, B, C) __builtin_amdgcn_mfma_f32_16x16x32_f16((A), (B), (C), 0, 0, 0)

// Issue one chunk's 4 loads (order fixed: asm volatile; no cache flags).
#define ISSUE(slot) do {                                                      \
    asm volatile("buffer_load_dwordx4 %0, %1, %2, 0 offen"                    \
                 : "=v"(LXA[slot]) : "v"(voff), "s"(srdx));                   \
    asm volatile("buffer_load_dwordx4 %0, %1, %2, 0 offen offset:16"          \
                 : "=v"(LXB[slot]) : "v"(voff), "s"(srdx));                   \
    asm volatile("buffer_load_dwordx4 %0, %1, %2, 0 offen"                    \
                 : "=v"(LYA[slot]) : "v"(voff), "s"(srdy));                   \
    asm volatile("buffer_load_dwordx4 %0, %1, %2, 0 offen offset:16"          \
                 : "=v"(LYB[slot]) : "v"(voff), "s"(srdy));                   \
    voff += CHSTEP;                                                           \
} while (0)

// vconv for out-chunk m (at iteration c = m+2): LDS-only, no vmem dep.
#define VCONV(C) do {                                                         \
    const _Float16* rp = rbase + ((((C) + qh) & 1) << 4);                     \
    const h8 B0 = *(const h8*)(rp + 0 * PSTR);   /* ds_read_b128 x4 */        \
    const h8 B1 = *(const h8*)(rp + 1 * PSTR);                                \
    const h8 B2 = *(const h8*)(rp + 2 * PSTR);                                \
    const h8 B3 = *(const h8*)(rp + 3 * PSTR);                                \
    const f32x4 aS  = MFMA16(wvA, B0, zz);                                    \
    const f32x4 aD  = MFMA16(wvA, B1, zz);                                    \
    const f32x4 aS2 = MFMA16(wvA, B2, zz);                                    \
    const f32x4 aD2 = MFMA16(wvA, B3, zz);                                    \
    local += mapsum(aS, aD, aS2, aD2, cv);                                    \
} while (0)

__global__ __launch_bounds__(NT, 4) void ssim_tile_kernel(
    const float* __restrict__ x, const float* __restrict__ y,
    float* __restrict__ partials)
{
    __shared__ __align__(16) _Float16 Ht[4 * WSTR];   // 20480 B
    __shared__ float wave_sums[NT / 64];

    const int tid = threadIdx.x;
    const int l = tid & 63, wid = tid >> 6;
    const int q = l >> 4, fc = l & 15;
    const int ql = q & 1, qh = q >> 1;

    // XCD-aware bijective swizzle (NBLK=768, 768%8==0): XCD k gets sids
    // [96k, 96k+96) = 6 whole planes -> halos are per-XCD L2 hits.
    const int bid = blockIdx.x;
    const int sid = (bid & 7) * (NBLK / 8) + (bid >> 3);
    const int plane = sid >> 4;                 // 16 blocks per plane
    const int rem = sid & 15;
    const int by = rem >> 3, bx = rem & 7;

    const i32x4 srdx = make_srd(x + (size_t)plane * IMG_H * IMG_W);
    const i32x4 srdy = make_srd(y + (size_t)plane * IMG_H * IMG_W);
    const int C0 = bx * TX;
    const int R0 = by * TYS;
    const int c0 = 16 * wid;                    // this wave's out-col base
    const int gcol = C0 + c0 - 8 + 8 * q;       // A-frag global col start
    // Row OOB -> voffset outside [0,NUMREC) -> HW returns 0 (zero-pad).
    // Col OOB lanes (gcol=-8 or 512): permanently-OOB voffset.
    int voff = ((unsigned)gcol < (unsigned)IMG_W)
             ? (((R0 - RAD + fc) << 11) + (gcol << 2)) : 0x60000000;

    // ---- Prologue: issue chunks 0,1,2 into ring slots 0,1,2 ----
    f32x4 LXA[3], LXB[3], LYA[3], LYB[3];
    ISSUE(0); ISSUE(1); ISSUE(2);

    // ---- Weight setup (executes under the 12 in-flight loads) ----
    float s2w = 0.f;
    #pragma unroll
    for (int k = 0; k <= 10; ++k) s2w += (float)(_Float16)wbandf(k);
    const float cv = 1.f / (s2w * s2w);

    h8 whB, wvA;                 // hconv B-frag w[t-u-3], vconv A-frag w[t-u]
    #pragma unroll
    for (int e = 0; e < 8; ++e) {
        whB[e] = (_Float16)wbandf(8 * q + e - fc - 3);
        wvA[e] = (_Float16)wbandf(8 * q + e - fc);
    }

    _Float16* const Hw = Ht + wid * WSTR;                    // wave's region
    _Float16* const hwr = Hw + fc * CSTR + 4 * q;            // write base (+slot*16)
    const _Float16* const rbase = Hw + fc * CSTR + 8 * ql;   // read base (+slot*16)

    const f32x4 zz = {0.f, 0.f, 0.f, 0.f};
    float local = 0.f;

    // ---- Main loop: vconv m=c-2 (LDS-only) | wait chunk c | copy ring,
    //      issue c+3 early | hconv c ----
    #pragma unroll
    for (int c = 0; c < NCH; ++c) {
        if (c >= 2) VCONV(c);            // reads Ht chunks c-2 (slot c&1), c-1
        if (c <= NCH - 3) vwait<8>();    // retire chunk c (ring depth 3)
        else if (c == NCH - 2) vwait<4>();
        else vwait<0>();
        // copy retired slot to locals, then refill EARLY (loads fly under
        // the hconv MFMAs below; SSA keeps old values correct)
        const f32x4 xa = LXA[c % 3], xb = LXB[c % 3];
        const f32x4 ya = LYA[c % 3], yb = LYB[c % 3];
        if (c + 3 < NCH) ISSUE(c % 3);
        // hconv chunk c -> LDS slot c&1 (overwrites chunk c-2 AFTER the
        // VCONV reads above; same-wave DS ops execute in order)
        hconv_chunk(xa, xb, ya, yb, whB, hwr + ((c & 1) << 4));
    }

    // ---- Epilogue: out chunk m=NCH-2 (reads Ht chunks NCH-2, NCH-1) ----
    VCONV(NCH);

    // ---- Block reduction -> one partial per block ----
    #pragma unroll
    for (int off = 32; off > 0; off >>= 1)
        local += __shfl_down(local, off, 64);
    if (l == 0) wave_sums[wid] = local;
    __syncthreads();
    if (tid == 0) {
        const float s = wave_sums[0] + wave_sums[1] + wave_sums[2] + wave_sums[3];
        partials[bid] = s;
    }
}

__global__ __launch_bounds__(256) void ssim_finalize_kernel(
    const float* __restrict__ partials, float* __restrict__ out)
{
    const int tid = threadIdx.x;
    double s = 0.0;
    #pragma unroll 4
    for (int i = tid; i < NBLK; i += 256) s += (double)partials[i];
    #pragma unroll
    for (int off = 32; off > 0; off >>= 1)
        s += __shfl_down(s, off, 64);
    __shared__ double ws_[256 / 64];
    const int lane = tid & 63, wv = tid >> 6;
    if (lane == 0) ws_[wv] = s;
    __syncthreads();
    if (tid == 0) {
        const double t = ws_[0] + ws_[1] + ws_[2] + ws_[3];
        const double n = (double)PLANES * IMG_H * IMG_W;
        out[0] = (float)(1.0 - t / n);
    }
}

extern "C" void kernel_launch(void* const* d_in, const int* in_sizes, int n_in,
                              void* d_out, int out_size, void* d_ws, size_t ws_size,
                              hipStream_t stream)
{
    const float* x = (const float*)d_in[0];
    const float* y = (const float*)d_in[1];
    float* out = (float*)d_out;
    float* partials = (float*)d_ws;   // NBLK floats, fully overwritten each call

    ssim_tile_kernel<<<dim3(NBLK, 1, 1), NT, 0, stream>>>(x, y, partials);
    ssim_finalize_kernel<<<1, 256, 0, stream>>>(partials, out);
}